// Round 1
// baseline (236.985 us; speedup 1.0000x reference)
//
#include <hip/hip_runtime.h>

// AugmentedNeuralODE, round 14: replace exp2+rcp sigmoid-tanh with a
// Pade[7/6] rational tanh (clamp +-5, max err 1.3e-4 << bf16-W2's 4e-3).
// Counter evidence (R13): VALUBusy 62% == (155 VALU*2 + 128 trans*16)/3760
// -> wave64 transcendentals issue-block ~16 cyc; trans is 54% of wall.
// Rational form: 2 rcp + 11 VALU per pair vs 4 trans + 2 VALU
// -> -448 issue cyc/feval (-12%) + shorter latency chains.
// K2C folding and 1-2q / -2*W3 algebra removed (tanh feeds MFMA/W3 raw).
// Structure otherwise == R13: 1024x64, 1 wave/SIMD, W2+b2 in AGPRs,
// zero LDS/barriers, interleaved L1->MFMA per K-slab, independent x/y rcps.

#define HID 128
#define TT  8
#define F(a,b) ((float)((double)(a)/(double)(b)))

typedef __attribute__((ext_vector_type(8))) short bf16x8;
typedef __attribute__((ext_vector_type(4))) float f32x4;
typedef __attribute__((ext_vector_type(2))) float f32x2;

union Frag { bf16x8 v; unsigned short u[8]; unsigned int d[4]; };

__device__ __forceinline__ f32x2 bc(float s) { return f32x2{s, s}; }
__device__ __forceinline__ f32x2 pk_fma(f32x2 a, f32x2 b, f32x2 c) {
#if __has_builtin(__builtin_elementwise_fma)
  return __builtin_elementwise_fma(a, b, c);
#else
  return a * b + c;
#endif
}
__device__ __forceinline__ unsigned short f2bf(float f) {
  unsigned u = __builtin_bit_cast(unsigned, f);
  u += 0x7FFFu + ((u >> 16) & 1u);          // RNE
  return (unsigned short)(u >> 16);
}
// packed bf16 pair: lo = a, hi = b
__device__ __forceinline__ unsigned pack2bf(float a, float b) {
#if __has_builtin(__builtin_amdgcn_cvt_pk_bf16_f32)
  auto pk = __builtin_amdgcn_cvt_pk_bf16_f32(a, b);   // v_cvt_pk_bf16_f32
  return __builtin_bit_cast(unsigned, pk);
#else
  unsigned ua = __builtin_bit_cast(unsigned, a);
  unsigned ub = __builtin_bit_cast(unsigned, b);
  ua += 0x7FFFu + ((ua >> 16) & 1u);
  ub += 0x7FFFu + ((ub >> 16) & 1u);
  return __builtin_amdgcn_perm(ub, ua, 0x07060302u);
#endif
}
// tanh via Pade[7/6] continued-fraction rational; input clamped to +-5.
// tanh(x) ~= x*(135135 + 17325 x^2 + 378 x^4 + x^6)
//            / (135135 + 62370 x^2 + 3150 x^4 + 28 x^6)
// max err <= 1.3e-4 on clamped range. 2 trans (separate rcp per element,
// independent x/y chains -- R12 lesson) + 11 VALU per pair.
__device__ __forceinline__ f32x2 tanh_pade(f32x2 x) {
  f32x2 cl = __builtin_elementwise_max(
      __builtin_elementwise_min(x, bc(5.0f)), bc(-5.0f));
  f32x2 x2 = cl * cl;
  f32x2 n = x2 + bc(378.0f);
  n = pk_fma(n, x2, bc(17325.0f));
  n = pk_fma(n, x2, bc(135135.0f));
  f32x2 d = pk_fma(x2, bc(28.0f), bc(3150.0f));
  d = pk_fma(d, x2, bc(62370.0f));
  d = pk_fma(d, x2, bc(135135.0f));
  f32x2 xn = cl * n;
  f32x2 r;
  r.x = __builtin_amdgcn_rcpf(d.x);
  r.y = __builtin_amdgcn_rcpf(d.y);
  return xn * r;
}

__global__ __launch_bounds__(64, 1) void node_kernel(
    const float* __restrict__ r0, const float* __restrict__ tarr,
    const float* __restrict__ W1, const float* __restrict__ b1,
    const float* __restrict__ W2, const float* __restrict__ b2,
    const float* __restrict__ W3, const float* __restrict__ b3,
    float* __restrict__ out)
{
  const int lane = (int)(threadIdx.x & 63u);
  const int quad = lane >> 4;          // 0..3
  const int m16  = lane & 15;          // my sample (column)
  const int s    = (int)blockIdx.x * 16 + m16;

  // ---- one-time preloads (raw weights, no K2C folding) ----
  // W1 for my 32 units k = kk*32 + quad*8 + j (16 pairs) -- arch VGPRs (128)
  f32x2 w1x[16], w1y[16], w1t[16], bb1[16];
  #pragma unroll
  for (int kk = 0; kk < 4; ++kk)
    #pragma unroll
    for (int p = 0; p < 4; ++p) {
      int i = kk * 32 + quad * 8 + 2 * p;
      int idx = kk * 4 + p;
      w1x[idx] = f32x2{W1[0 * HID + i], W1[0 * HID + i + 1]};
      w1y[idx] = f32x2{W1[1 * HID + i], W1[1 * HID + i + 1]};
      w1t[idx] = f32x2{W1[4 * HID + i], W1[4 * HID + i + 1]};
      bb1[idx] = f32x2{b1[i], b1[i + 1]};
    }
  // W2 A-frags for ALL 8 out-tiles -> pinned into AGPRs (128 regs)
  Frag W2f[8][4];
  #pragma unroll
  for (int t = 0; t < 8; ++t) {
    int o = t * 16 + m16;
    #pragma unroll
    for (int kk = 0; kk < 4; ++kk) {
      #pragma unroll
      for (int j = 0; j < 8; ++j)
        W2f[t][kk].u[j] = f2bf(W2[(kk * 32 + quad * 8 + j) * HID + o]);
      asm volatile("" : "+a"(W2f[t][kk].v));   // park in AGPR (MFMA A-src)
    }
  }
  // acc-init = b2 -> AGPR (32, MFMA C-src); W3 row pairs (raw)
  f32x4 b2i[8];
  f32x2 w3p[8][4];                      // {w3x, w3y} per h2 row
  #pragma unroll
  for (int t = 0; t < 8; ++t) {
    #pragma unroll
    for (int rr = 0; rr < 4; ++rr) {
      int o = t * 16 + quad * 4 + rr;
      b2i[t][rr] = b2[o];
      w3p[t][rr] = f32x2{W3[o * 2 + 0], W3[o * 2 + 1]};
    }
    asm volatile("" : "+a"(b2i[t]));
  }
  const f32x2 b3v = f32x2{b3[0], b3[1]};

  f32x2 S = f32x2{r0[2 * s + 0], r0[2 * s + 1]};
  if (lane < 16) *(float2*)&out[(s * TT + 0) * 2] = make_float2(S.x, S.y);

  auto feval = [&](float tt, f32x2 st) -> f32x2 {
    const f32x2 sx = bc(st.x), sy = bc(st.y), tv = bc(tt);
    // ---- interleaved: per K-slab, 4 tanh-pairs -> B-frag -> 8 MFMAs ----
    f32x4 acc[8];
    #pragma unroll
    for (int kk = 0; kk < 4; ++kk) {
      unsigned pd[4];
      #pragma unroll
      for (int p = 0; p < 4; ++p) {
        int idx = kk * 4 + p;
        f32x2 a = pk_fma(sx, w1x[idx], bb1[idx]);
        a = pk_fma(sy, w1y[idx], a);
        a = pk_fma(tv, w1t[idx], a);
        f32x2 h = tanh_pade(a);
        pd[p] = pack2bf(h.x, h.y);
      }
      Frag bv;
      bv.d[0] = pd[0]; bv.d[1] = pd[1]; bv.d[2] = pd[2]; bv.d[3] = pd[3];
      if (kk == 0) {
        #pragma unroll
        for (int t = 0; t < 8; ++t)
          acc[t] = __builtin_amdgcn_mfma_f32_16x16x32_bf16(
              W2f[t][0].v, bv.v, b2i[t], 0, 0, 0);
      } else {
        #pragma unroll
        for (int t = 0; t < 8; ++t)
          acc[t] = __builtin_amdgcn_mfma_f32_16x16x32_bf16(
              W2f[t][kk].v, bv.v, acc[t], 0, 0, 0);
      }
    }
    // ---- epilogue: vs = sum(w3 * tanh(acc)), rational tanh ----
    f32x2 vsa[2] = {bc(0.f), bc(0.f)};
    #pragma unroll
    for (int t = 0; t < 8; ++t)
      #pragma unroll
      for (int p = 0; p < 2; ++p) {
        f32x2 av = f32x2{acc[t][2 * p], acc[t][2 * p + 1]};
        f32x2 th = tanh_pade(av);
        vsa[t & 1] = pk_fma(bc(th.x), w3p[t][2 * p + 0], vsa[t & 1]);
        vsa[t & 1] = pk_fma(bc(th.y), w3p[t][2 * p + 1], vsa[t & 1]);
      }
    f32x2 vs = vsa[0] + vsa[1];
    // cross-quad reduce (sample m16 partials live at lanes m16+16q)
    float px = vs.x, py = vs.y;
    px += __shfl_xor(px, 16); py += __shfl_xor(py, 16);
    px += __shfl_xor(px, 32); py += __shfl_xor(py, 32);
    return f32x2{px, py} + b3v;
  };

  #pragma unroll 1
  for (int iv = 0; iv < TT - 1; ++iv) {
    float t0 = tarr[iv], t1 = tarr[iv + 1];
    float dt = (t1 - t0) * 0.5f;
    #pragma unroll 1
    for (int ss = 0; ss < 2; ++ss) {
      float tb = (ss == 0) ? t0 : (t0 + dt);
      const f32x2 dtv = bc(dt);
      f32x2 k1 = feval(tb, S);
      f32x2 k2 = feval(tb + dt * F(1,5), pk_fma(bc(dt * F(1,5)), k1, S));
      f32x2 a3 = pk_fma(bc(F(9,40)), k2, bc(F(3,40)) * k1);
      f32x2 k3 = feval(tb + dt * F(3,10), pk_fma(dtv, a3, S));
      f32x2 a4 = pk_fma(bc(F(44,45)), k1,
                 pk_fma(bc(-F(56,15)), k2, bc(F(32,9)) * k3));
      f32x2 k4 = feval(tb + dt * F(4,5), pk_fma(dtv, a4, S));
      f32x2 a5 = pk_fma(bc(F(19372,6561)), k1,
                 pk_fma(bc(-F(25360,2187)), k2,
                 pk_fma(bc(F(64448,6561)), k3, bc(-F(212,729)) * k4)));
      f32x2 k5 = feval(tb + dt * F(8,9), pk_fma(dtv, a5, S));
      f32x2 a6 = pk_fma(bc(F(9017,3168)), k1,
                 pk_fma(bc(-F(355,33)), k2,
                 pk_fma(bc(F(46732,5247)), k3,
                 pk_fma(bc(F(49,176)), k4, bc(-F(5103,18656)) * k5))));
      f32x2 k6 = feval(tb + dt, pk_fma(dtv, a6, S));
      f32x2 fin = pk_fma(bc(F(35,384)), k1,
                  pk_fma(bc(F(500,1113)), k3,
                  pk_fma(bc(F(125,192)), k4,
                  pk_fma(bc(-F(2187,6784)), k5, bc(F(11,84)) * k6))));
      S = pk_fma(dtv, fin, S);
    }
    if (lane < 16) *(float2*)&out[(s * TT + iv + 1) * 2] = make_float2(S.x, S.y);
  }
}

extern "C" void kernel_launch(void* const* d_in, const int* in_sizes, int n_in,
                              void* d_out, int out_size, void* d_ws, size_t ws_size,
                              hipStream_t stream) {
  const float* r0 = (const float*)d_in[0];
  const float* t  = (const float*)d_in[1];
  const float* W1 = (const float*)d_in[2];
  const float* b1 = (const float*)d_in[3];
  const float* W2 = (const float*)d_in[4];
  const float* b2 = (const float*)d_in[5];
  const float* W3 = (const float*)d_in[6];
  const float* b3 = (const float*)d_in[7];
  float* out = (float*)d_out;
  const int B = in_sizes[0] / 2;        // 16384
  dim3 grid(B / 16), block(64);         // 1024 blocks x 64 threads (1 wave)
  node_kernel<<<grid, block, 0, stream>>>(r0, t, W1, b1, W2, b2, W3, b3, out);
}

// Round 2
// 199.264 us; speedup vs baseline: 1.1893x; 1.1893x over previous
//
#include <hip/hip_runtime.h>

// AugmentedNeuralODE, round 15: revert R14's Pade tanh (trans->VALU trade
// cost +52%: added 288 pk-ops/feval cost ~4.2cyc each, removed exp2s bought
// ~0 -- VALU issue is the wall, trans mostly hides). Back to R13's exp2
// sigmoid, restructured for 2 waves/SIMD:
//   * 128-thread blocks (2 waves), 1024 blocks -> 2048 waves = 2/SIMD
//     (R13: 1024 waves = 1/SIMD, occupancy 11%, 24% idle unhidable).
//   * Unit-split per feval: wave w computes K-slabs {2w,2w+1} of h1
//     (8 tanh-pairs vs 16) and out-tiles {4w..4w+3} (16 MFMA, 8 ep pairs).
//   * B-frag exchange via LDS (lane-matched raw copy, 2x b128 each way),
//     2-float cross-wave v-reduce. 2 barriers/feval, parity ping-pong
//     (any buffer rewrite is >=2 barriers after its last read).
//   * Per-wave regs ~halve (~170 VGPR + 80 AGPR <= 256) so launch_bounds
//     (128,2) actually fits 2 waves/SIMD.
// Same arithmetic as R13 (same K-order MFMA chain) -> absmax identical.

#define HID 128
#define TT  8
#define F(a,b) ((float)((double)(a)/(double)(b)))
#define K2C 2.8853900817779268f   // 2*log2(e), folded into W1/b1/W2/b2

typedef __attribute__((ext_vector_type(8))) short bf16x8;
typedef __attribute__((ext_vector_type(4))) float f32x4;
typedef __attribute__((ext_vector_type(2))) float f32x2;

union Frag { bf16x8 v; unsigned short u[8]; unsigned int d[4]; };

__device__ __forceinline__ f32x2 bc(float s) { return f32x2{s, s}; }
__device__ __forceinline__ f32x2 pk_fma(f32x2 a, f32x2 b, f32x2 c) {
#if __has_builtin(__builtin_elementwise_fma)
  return __builtin_elementwise_fma(a, b, c);
#else
  return a * b + c;
#endif
}
__device__ __forceinline__ float exp2_fast(float x) {
#if __has_builtin(__builtin_amdgcn_exp2f)
  return __builtin_amdgcn_exp2f(x);
#else
  return __builtin_exp2f(x);
#endif
}
__device__ __forceinline__ unsigned short f2bf(float f) {
  unsigned u = __builtin_bit_cast(unsigned, f);
  u += 0x7FFFu + ((u >> 16) & 1u);          // RNE
  return (unsigned short)(u >> 16);
}
// packed bf16 pair: lo = a, hi = b
__device__ __forceinline__ unsigned pack2bf(float a, float b) {
#if __has_builtin(__builtin_amdgcn_cvt_pk_bf16_f32)
  auto pk = __builtin_amdgcn_cvt_pk_bf16_f32(a, b);   // v_cvt_pk_bf16_f32
  return __builtin_bit_cast(unsigned, pk);
#else
  unsigned ua = __builtin_bit_cast(unsigned, a);
  unsigned ub = __builtin_bit_cast(unsigned, b);
  ua += 0x7FFFu + ((ua >> 16) & 1u);
  ub += 0x7FFFu + ((ub >> 16) & 1u);
  return __builtin_amdgcn_perm(ub, ua, 0x07060302u);
#endif
}
// u pre-scaled by 2*log2(e): q = 1/(exp2(u)+1), SEPARATE rcp per element
// (independent x/y chains -- R12 lesson).
__device__ __forceinline__ f32x2 sig_q(f32x2 u) {
  f32x2 e;
  e.x = exp2_fast(u.x);
  e.y = exp2_fast(u.y);
  f32x2 d = e + bc(1.0f);
  f32x2 q;
  q.x = __builtin_amdgcn_rcpf(d.x);
  q.y = __builtin_amdgcn_rcpf(d.y);
  return q;
}
// tanh(x) = 1 - 2q
__device__ __forceinline__ f32x2 tanh_pre(f32x2 u) {
  return pk_fma(bc(-2.0f), sig_q(u), bc(1.0f));
}

__global__ __launch_bounds__(128, 2) void node_kernel(
    const float* __restrict__ r0, const float* __restrict__ tarr,
    const float* __restrict__ W1, const float* __restrict__ b1,
    const float* __restrict__ W2, const float* __restrict__ b2,
    const float* __restrict__ W3, const float* __restrict__ b3,
    float* __restrict__ out)
{
  const int tid  = (int)threadIdx.x;
  const int w    = tid >> 6;           // wave id 0/1
  const int lane = tid & 63;
  const int quad = lane >> 4;          // 0..3
  const int m16  = lane & 15;          // my sample (column)
  const int s    = (int)blockIdx.x * 16 + m16;

  // LDS: B-frag exchange (parity ping-pong) + cross-wave v reduce
  __shared__ unsigned fragbuf[2][2][64][8];   // [parity][wave][lane][dw]
  __shared__ float    vredbuf[2][2][16][2];   // [parity][wave][m16][xy]

  // ---- one-time preloads, K2-folded ----
  // W1 for my wave's 32 units: global slabs {2w, 2w+1}, k = slab*32+quad*8+j
  f32x2 w1x[8], w1y[8], w1t[8], bb1[8];
  #pragma unroll
  for (int kkl = 0; kkl < 2; ++kkl)
    #pragma unroll
    for (int p = 0; p < 4; ++p) {
      int i = (2 * w + kkl) * 32 + quad * 8 + 2 * p;
      int idx = kkl * 4 + p;
      w1x[idx] = f32x2{W1[0 * HID + i], W1[0 * HID + i + 1]} * bc(K2C);
      w1y[idx] = f32x2{W1[1 * HID + i], W1[1 * HID + i + 1]} * bc(K2C);
      w1t[idx] = f32x2{W1[4 * HID + i], W1[4 * HID + i + 1]} * bc(K2C);
      bb1[idx] = f32x2{b1[i], b1[i + 1]} * bc(K2C);
    }
  // W2 A-frags: my 4 out-tiles (t = 4w+tl), ALL 4 K-slabs -> AGPRs (64)
  Frag W2f[4][4];
  #pragma unroll
  for (int tl = 0; tl < 4; ++tl) {
    int o = (4 * w + tl) * 16 + m16;
    #pragma unroll
    for (int kk = 0; kk < 4; ++kk) {
      #pragma unroll
      for (int j = 0; j < 8; ++j)
        W2f[tl][kk].u[j] = f2bf(W2[(kk * 32 + quad * 8 + j) * HID + o] * K2C);
      asm volatile("" : "+a"(W2f[tl][kk].v));   // park in AGPR (MFMA A-src)
    }
  }
  // acc-init = b2*K2 -> AGPR (16); W3 as -2*w3 pairs + w3-sum (my rows)
  f32x4 b2i[4];
  f32x2 w3n2[4][4];
  f32x2 w3s = bc(0.f);
  #pragma unroll
  for (int tl = 0; tl < 4; ++tl) {
    #pragma unroll
    for (int rr = 0; rr < 4; ++rr) {
      int o = (4 * w + tl) * 16 + quad * 4 + rr;
      b2i[tl][rr] = b2[o] * K2C;
      f32x2 w3 = f32x2{W3[o * 2 + 0], W3[o * 2 + 1]};
      w3s += w3;
      w3n2[tl][rr] = w3 * bc(-2.f);
    }
    asm volatile("" : "+a"(b2i[tl]));
  }
  const f32x2 b3v = f32x2{b3[0], b3[1]};

  f32x2 S = f32x2{r0[2 * s + 0], r0[2 * s + 1]};
  if (w == 0 && lane < 16)
    *(float2*)&out[(s * TT + 0) * 2] = make_float2(S.x, S.y);

  int par = 0;

  auto feval = [&](float tt, f32x2 st) -> f32x2 {
    const f32x2 sx = bc(st.x), sy = bc(st.y), tv = bc(tt);
    // ---- L1: my 2 slabs -> 8 tanh-pairs -> 2 packed B-frags ----
    Frag own0, own1;
    #pragma unroll
    for (int kkl = 0; kkl < 2; ++kkl) {
      unsigned pd[4];
      #pragma unroll
      for (int p = 0; p < 4; ++p) {
        int idx = kkl * 4 + p;
        f32x2 a = pk_fma(sx, w1x[idx], bb1[idx]);
        a = pk_fma(sy, w1y[idx], a);
        a = pk_fma(tv, w1t[idx], a);
        f32x2 h = tanh_pre(a);
        pd[p] = pack2bf(h.x, h.y);
      }
      Frag& f = kkl ? own1 : own0;
      f.d[0] = pd[0]; f.d[1] = pd[1]; f.d[2] = pd[2]; f.d[3] = pd[3];
    }
    // exchange B-frags with partner wave (lane-matched raw copy)
    unsigned* dst = &fragbuf[par][w][lane][0];
    *(uint4*)(dst + 0) = *(uint4*)&own0.d[0];
    *(uint4*)(dst + 4) = *(uint4*)&own1.d[0];
    __syncthreads();
    const unsigned* src = &fragbuf[par][w ^ 1][lane][0];
    Frag par0, par1;
    *(uint4*)&par0.d[0] = *(const uint4*)(src + 0);
    *(uint4*)&par1.d[0] = *(const uint4*)(src + 4);
    // global slab order 0..3 (same K-order as R13 -> identical rounding)
    Frag g0, g1, g2, g3;
    if (w == 0) { g0 = own0; g1 = own1; g2 = par0; g3 = par1; }
    else        { g0 = par0; g1 = par1; g2 = own0; g3 = own1; }
    // ---- MFMA: my 4 out-tiles over all 4 slabs ----
    f32x4 acc[4];
    #pragma unroll
    for (int tl = 0; tl < 4; ++tl)
      acc[tl] = __builtin_amdgcn_mfma_f32_16x16x32_bf16(
          W2f[tl][0].v, g0.v, b2i[tl], 0, 0, 0);
    #pragma unroll
    for (int tl = 0; tl < 4; ++tl)
      acc[tl] = __builtin_amdgcn_mfma_f32_16x16x32_bf16(
          W2f[tl][1].v, g1.v, acc[tl], 0, 0, 0);
    #pragma unroll
    for (int tl = 0; tl < 4; ++tl)
      acc[tl] = __builtin_amdgcn_mfma_f32_16x16x32_bf16(
          W2f[tl][2].v, g2.v, acc[tl], 0, 0, 0);
    #pragma unroll
    for (int tl = 0; tl < 4; ++tl)
      acc[tl] = __builtin_amdgcn_mfma_f32_16x16x32_bf16(
          W2f[tl][3].v, g3.v, acc[tl], 0, 0, 0);
    // ---- epilogue: vs = w3s + sum((-2*w3) * q) over my 4 tiles ----
    f32x2 vsa[2] = {w3s, bc(0.f)};
    #pragma unroll
    for (int tl = 0; tl < 4; ++tl)
      #pragma unroll
      for (int p = 0; p < 2; ++p) {
        f32x2 av = f32x2{acc[tl][2 * p], acc[tl][2 * p + 1]};
        f32x2 q = sig_q(av);
        vsa[tl & 1] = pk_fma(bc(q.x), w3n2[tl][2 * p + 0], vsa[tl & 1]);
        vsa[tl & 1] = pk_fma(bc(q.y), w3n2[tl][2 * p + 1], vsa[tl & 1]);
      }
    f32x2 vs = vsa[0] + vsa[1];
    // cross-quad reduce within wave (sample m16 partials at lanes m16+16q)
    float px = vs.x, py = vs.y;
    px += __shfl_xor(px, 16); py += __shfl_xor(py, 16);
    px += __shfl_xor(px, 32); py += __shfl_xor(py, 32);
    // cross-wave reduce via LDS
    if (lane < 16) {
      vredbuf[par][w][m16][0] = px;
      vredbuf[par][w][m16][1] = py;
    }
    __syncthreads();
    float2 o = *(float2*)&vredbuf[par][w ^ 1][m16][0];
    par ^= 1;
    return f32x2{px + o.x, py + o.y} + b3v;
  };

  #pragma unroll 1
  for (int iv = 0; iv < TT - 1; ++iv) {
    float t0 = tarr[iv], t1 = tarr[iv + 1];
    float dt = (t1 - t0) * 0.5f;
    #pragma unroll 1
    for (int ss = 0; ss < 2; ++ss) {
      float tb = (ss == 0) ? t0 : (t0 + dt);
      const f32x2 dtv = bc(dt);
      f32x2 k1 = feval(tb, S);
      f32x2 k2 = feval(tb + dt * F(1,5), pk_fma(bc(dt * F(1,5)), k1, S));
      f32x2 a3 = pk_fma(bc(F(9,40)), k2, bc(F(3,40)) * k1);
      f32x2 k3 = feval(tb + dt * F(3,10), pk_fma(dtv, a3, S));
      f32x2 a4 = pk_fma(bc(F(44,45)), k1,
                 pk_fma(bc(-F(56,15)), k2, bc(F(32,9)) * k3));
      f32x2 k4 = feval(tb + dt * F(4,5), pk_fma(dtv, a4, S));
      f32x2 a5 = pk_fma(bc(F(19372,6561)), k1,
                 pk_fma(bc(-F(25360,2187)), k2,
                 pk_fma(bc(F(64448,6561)), k3, bc(-F(212,729)) * k4)));
      f32x2 k5 = feval(tb + dt * F(8,9), pk_fma(dtv, a5, S));
      f32x2 a6 = pk_fma(bc(F(9017,3168)), k1,
                 pk_fma(bc(-F(355,33)), k2,
                 pk_fma(bc(F(46732,5247)), k3,
                 pk_fma(bc(F(49,176)), k4, bc(-F(5103,18656)) * k5))));
      f32x2 k6 = feval(tb + dt, pk_fma(dtv, a6, S));
      f32x2 fin = pk_fma(bc(F(35,384)), k1,
                  pk_fma(bc(F(500,1113)), k3,
                  pk_fma(bc(F(125,192)), k4,
                  pk_fma(bc(-F(2187,6784)), k5, bc(F(11,84)) * k6))));
      S = pk_fma(dtv, fin, S);
    }
    if (w == 0 && lane < 16)
      *(float2*)&out[(s * TT + iv + 1) * 2] = make_float2(S.x, S.y);
  }
}

extern "C" void kernel_launch(void* const* d_in, const int* in_sizes, int n_in,
                              void* d_out, int out_size, void* d_ws, size_t ws_size,
                              hipStream_t stream) {
  const float* r0 = (const float*)d_in[0];
  const float* t  = (const float*)d_in[1];
  const float* W1 = (const float*)d_in[2];
  const float* b1 = (const float*)d_in[3];
  const float* W2 = (const float*)d_in[4];
  const float* b2 = (const float*)d_in[5];
  const float* W3 = (const float*)d_in[6];
  const float* b3 = (const float*)d_in[7];
  float* out = (float*)d_out;
  const int B = in_sizes[0] / 2;        // 16384
  dim3 grid(B / 16), block(128);        // 1024 blocks x 2 waves -> 2/SIMD
  node_kernel<<<grid, block, 0, stream>>>(r0, t, W1, b1, W2, b2, W3, b3, out);
}